// Round 10
// baseline (646.583 us; speedup 1.0000x reference)
//
#include <hip/hip_runtime.h>
#include <math.h>

// Fused soft-argmax centroid over [B,K,128,128] fp32, two inputs.
// Single launch, PARTS=4: 8192 blocks x 256 threads, each block reduces a
// 32-row quarter of one (input,b,k) unit with nontemporal float4 loads.
// Lock-free finish: each part atomicExch-publishes {sx,sy} then s (release
// order, s last = ready flag; real s ~2048 > 0.5, 0xAA-poison float =
// -3e-13 < 0.5). Any block observing all four s-slots ready computes the
// identical final result and writes it -- no second kernel, no ws init.

#define HM_H 128
#define HM_W 128
#define PARTS 4

typedef float vf4 __attribute__((ext_vector_type(4)));

__global__ __launch_bounds__(256) void centroid_nt4(
    const float* __restrict__ hm0,
    const float* __restrict__ hm1,
    float* __restrict__ ws,
    float* __restrict__ out,
    int BK)
{
    const int gb   = blockIdx.x;            // 0 .. 2*BK*PARTS-1
    const int part = gb & (PARTS - 1);
    const int u    = gb >> 2;               // unit 0 .. 2*BK-1
    const int bk   = (u >= BK) ? (u - BK) : u;
    const vf4* __restrict__ p =
        (const vf4*)(((u >= BK) ? hm1 : hm0) + (size_t)bk * (HM_H * HM_W))
        + part * 1024;                      // 32 rows = 1024 float4 per part
    const int t = threadIdx.x;

    const float colb = (float)((t << 2) & (HM_W - 1)); // column of lane's 4-group
    const float rowb = (float)(t >> 5);                // local row = rowb + 8m

    float s = 0.0f, sx = 0.0f, sy = 0.0f;

#pragma unroll
    for (int m = 0; m < 4; ++m) {
        const vf4 v = __builtin_nontemporal_load(&p[t + m * 256]);
        const float sv = (v[0] + v[1]) + (v[2] + v[3]);
        s  += sv;
        sx += (v[1] + 2.0f * v[2]) + 3.0f * v[3];
        sy += (float)(8 * m) * sv;
    }
    sx += colb * s;
    sy += (rowb + (float)(32 * part)) * s;  // global row offset of this part

    // ---- wave (64-lane) butterfly reduce ----
#pragma unroll
    for (int off = 32; off > 0; off >>= 1) {
        s  += __shfl_down(s,  off, 64);
        sx += __shfl_down(sx, off, 64);
        sy += __shfl_down(sy, off, 64);
    }

    __shared__ float ls[4], lx[4], ly[4];
    const int wid  = t >> 6;
    const int lane = t & 63;
    if (lane == 0) { ls[wid] = s; lx[wid] = sx; ly[wid] = sy; }
    __syncthreads();

    if (t == 0) {
        const float S = ls[0] + ls[1] + ls[2] + ls[3];
        const float X = lx[0] + lx[1] + lx[2] + lx[3];
        const float Y = ly[0] + ly[1] + ly[2] + ly[3];

        float* slot = ws + (size_t)u * (PARTS * 3);   // 12 floats per unit

        // publish: sx, sy first; fence; s last (device-scope atomics = ready flag)
        atomicExch(&slot[part * 3 + 1], X);
        atomicExch(&slot[part * 3 + 2], Y);
        __threadfence();
        atomicExch(&slot[part * 3 + 0], S);

        // try-finish: all four s-slots real? (real S ~2048; poison = -3e-13)
        const float s0 = atomicAdd(&slot[0], 0.0f);
        const float s1 = atomicAdd(&slot[3], 0.0f);
        const float s2 = atomicAdd(&slot[6], 0.0f);
        const float s3 = atomicAdd(&slot[9], 0.0f);
        if (s0 > 0.5f && s1 > 0.5f && s2 > 0.5f && s3 > 0.5f) {
            __threadfence();   // acquire: sx/sy of a ready part are final
            const float Xs = ((atomicAdd(&slot[1],  0.0f)  + atomicAdd(&slot[4],  0.0f))
                            + (atomicAdd(&slot[7],  0.0f)  + atomicAdd(&slot[10], 0.0f)));
            const float Ys = ((atomicAdd(&slot[2],  0.0f)  + atomicAdd(&slot[5],  0.0f))
                            + (atomicAdd(&slot[8],  0.0f)  + atomicAdd(&slot[11], 0.0f)));
            const float Ss = (s0 + s1) + (s2 + s3);
            // duplicate finishers (rare) compute identical values -- benign
            out[u * 2 + 0] = rintf(Xs / Ss);   // round-half-to-even == jnp.round
            out[u * 2 + 1] = rintf(Ys / Ss);
        }
    }
}

extern "C" void kernel_launch(void* const* d_in, const int* in_sizes, int n_in,
                              void* d_out, int out_size, void* d_ws, size_t ws_size,
                              hipStream_t stream) {
    const float* hm0 = (const float*)d_in[0];
    const float* hm1 = (const float*)d_in[1];
    float* out = (float*)d_out;
    float* ws  = (float*)d_ws;

    const int BK     = out_size / 4;     // B*K
    const int nunits = 2 * BK;           // 2048
    const int grid   = nunits * PARTS;   // 8192 blocks, single launch

    centroid_nt4<<<grid, 256, 0, stream>>>(hm0, hm1, ws, out, BK);
}

// Round 11
// 136.659 us; speedup vs baseline: 4.7314x; 4.7314x over previous
//
#include <hip/hip_runtime.h>
#include <math.h>

// Fused soft-argmax centroid over [B,K,128,128] fp32, two inputs.
// Proven-best configuration (round 8): 2048 blocks x 256 threads, one
// generation, 16 nontemporal float4 per thread (streaming reads, no cache
// allocate -> avoids L2/L3 churn; 43 -> 33 us). Single launch, no ws.

#define HM_H 128
#define HM_W 128

typedef float vf4 __attribute__((ext_vector_type(4)));

__global__ __launch_bounds__(256) void centroid_nt(
    const float* __restrict__ hm0,
    const float* __restrict__ hm1,
    float* __restrict__ out,
    int BK)
{
    const int u  = blockIdx.x;                 // 0 .. 2*BK-1
    const int bk = (u >= BK) ? (u - BK) : u;
    const vf4* __restrict__ p =
        (const vf4*)(((u >= BK) ? hm1 : hm0) + (size_t)bk * (HM_H * HM_W));
    const int t = threadIdx.x;

    const float colb = (float)((t << 2) & (HM_W - 1)); // column of lane's 4-group
    const float rowb = (float)(t >> 5);                // row of chunk m = rowb + 8m

    float s = 0.0f, sx = 0.0f, sy = 0.0f;

#pragma unroll
    for (int m = 0; m < 16; ++m) {
        const vf4 v = __builtin_nontemporal_load(&p[t + m * 256]);
        const float sv = (v[0] + v[1]) + (v[2] + v[3]);
        s  += sv;
        sx += (v[1] + 2.0f * v[2]) + 3.0f * v[3];
        sy += (float)(8 * m) * sv;             // global row = rowb + 8m
    }
    sx += colb * s;
    sy += rowb * s;

    // ---- wave (64-lane) butterfly reduce ----
    float ss = s;
#pragma unroll
    for (int off = 32; off > 0; off >>= 1) {
        ss += __shfl_down(ss, off, 64);
        sx += __shfl_down(sx, off, 64);
        sy += __shfl_down(sy, off, 64);
    }

    __shared__ float ls[4], lx[4], ly[4];
    const int wid  = t >> 6;
    const int lane = t & 63;
    if (lane == 0) { ls[wid] = ss; lx[wid] = sx; ly[wid] = sy; }
    __syncthreads();

    if (t == 0) {
        const float S = ls[0] + ls[1] + ls[2] + ls[3];
        const float X = lx[0] + lx[1] + lx[2] + lx[3];
        const float Y = ly[0] + ly[1] + ly[2] + ly[3];
        // out = [keypoint (BK*2) | tf_keypoint (BK*2)]
        out[u * 2 + 0] = rintf(X / S);   // round-half-to-even == jnp.round
        out[u * 2 + 1] = rintf(Y / S);
    }
}

extern "C" void kernel_launch(void* const* d_in, const int* in_sizes, int n_in,
                              void* d_out, int out_size, void* d_ws, size_t ws_size,
                              hipStream_t stream) {
    const float* hm0 = (const float*)d_in[0];
    const float* hm1 = (const float*)d_in[1];
    float* out = (float*)d_out;

    const int BK     = out_size / 4;   // B*K
    const int nunits = 2 * BK;         // 2048 blocks

    centroid_nt<<<nunits, 256, 0, stream>>>(hm0, hm1, out, BK);
}